// Round 9
// baseline (215.323 us; speedup 1.0000x reference)
//
#include <hip/hip_runtime.h>
#include <hip/hip_bf16.h>

#define IN_F 8192
#define OUT_F 8192
#define SEQ 64
#define LORA_R 16

typedef __attribute__((ext_vector_type(4))) float f32x4;
typedef __attribute__((ext_vector_type(4))) int i32x4;
typedef __attribute__((ext_vector_type(4))) unsigned short u16x4;
typedef _Float16 f16x2 __attribute__((ext_vector_type(2)));
typedef _Float16 f16x8 __attribute__((ext_vector_type(8)));

typedef __attribute__((address_space(3))) unsigned int lds_u32;
typedef const __attribute__((address_space(1))) unsigned int glb_u32;

__device__ __forceinline__ void gl_lds16(const void* g, void* l) {
    __builtin_amdgcn_global_load_lds((glb_u32*)g, (lds_u32*)l, 16, 0, 0);
}

#define VMCNT(n) asm volatile("s_waitcnt vmcnt(" #n ")" ::: "memory")

// ---- prep (measured, R5/R8 verbatim): xb = fp16(x); t partials = x@A^T (K/4). ----
__global__ __launch_bounds__(256) void k_prep(
    const float* __restrict__ x, const float* __restrict__ A,
    unsigned short* __restrict__ xb, float* __restrict__ t) {
    __shared__ float part[64];
    const int s = blockIdx.x >> 2, p = blockIdx.x & 3;
    const int w = threadIdx.x >> 6, lane = threadIdx.x & 63;
    const int kbase = p * 2048 + w * 512;
    const float* xr = x + s * IN_F + kbase;

    f32x4 xv[2];
    #pragma unroll
    for (int j = 0; j < 2; ++j) {
        xv[j] = *(const f32x4*)(xr + j * 256 + lane * 4);
        u16x4 h;
        h[0] = __builtin_bit_cast(unsigned short, (_Float16)xv[j].x);
        h[1] = __builtin_bit_cast(unsigned short, (_Float16)xv[j].y);
        h[2] = __builtin_bit_cast(unsigned short, (_Float16)xv[j].z);
        h[3] = __builtin_bit_cast(unsigned short, (_Float16)xv[j].w);
        *(u16x4*)(xb + s * IN_F + kbase + j * 256 + lane * 4) = h;
    }

    float acc[LORA_R];
    #pragma unroll
    for (int r = 0; r < LORA_R; ++r) acc[r] = 0.f;
    #pragma unroll
    for (int r = 0; r < LORA_R; ++r) {
        const float* ar = A + r * IN_F + kbase;
        #pragma unroll
        for (int j = 0; j < 2; ++j) {
            f32x4 av = *(const f32x4*)(ar + j * 256 + lane * 4);
            acc[r] = fmaf(xv[j].x, av.x, acc[r]);
            acc[r] = fmaf(xv[j].y, av.y, acc[r]);
            acc[r] = fmaf(xv[j].z, av.z, acc[r]);
            acc[r] = fmaf(xv[j].w, av.w, acc[r]);
        }
    }
    #pragma unroll
    for (int r = 0; r < LORA_R; ++r) {
        float v = acc[r];
        #pragma unroll
        for (int off = 32; off; off >>= 1) v += __shfl_down(v, off, 64);
        if (lane == 0) part[w * 16 + r] = v;
    }
    __syncthreads();
    if (threadIdx.x < 16)
        t[s * 64 + p * 16 + threadIdx.x] = part[threadIdx.x] + part[16 + threadIdx.x] +
                                           part[32 + threadIdx.x] + part[48 + threadIdx.x];
}

// ---- main: 512 blocks = 256 tiles x 2 K-halves; 512 thr = 8 waves; BK=128 ----
// LDS 78080 B -> 2 blocks/CU (TLP latency hiding). 32 iters/block.
// 3 buffers, depth-2 flight, counted vmcnt(3). Pure GEMM partials -> pb (no LoRA).
// XOR swizzle (16B slot ^= row&7) via pre-XOR'd global src; swizzled LDS reads.
// LDS: xs 3x[64*128]f16 @0 | wt 3x[32*64]int @49152 | scs [32][68]f16 @73728
// epilogue alias: accs[8][64*17] f32 over xs.
__global__ __launch_bounds__(512, 4) void k_main(
    const int* __restrict__ packed, const float* __restrict__ scales,
    const unsigned short* __restrict__ xb, float* __restrict__ pb) {
    __shared__ char lds[78080];
    _Float16* xs = (_Float16*)lds;               // 3 x 8192 f16
    int* wt = (int*)(lds + 49152);               // 3 x 2048 int
    _Float16* scs = (_Float16*)(lds + 73728);    // 32 x 68 f16
    float* accs = (float*)lds;

    const int tid = threadIdx.x;
    const int tile = blockIdx.x >> 1, kh = blockIdx.x & 1;
    const int n0 = tile * 32;
    const int w = tid >> 6, lane = tid & 63;
    const int nh = w >> 2, wkk = w & 3;
    const int q = lane >> 4, c16 = lane & 15;
    const int lr4 = lane >> 4, slot = lane & 15;

    // ---- scales for this K-half: f32 -> f16, staged once ----
    {
        int row = tid >> 4, g = tid & 15;
        f32x4 a = *(const f32x4*)(scales + (n0 + row) * (IN_F / 64) + kh * 64 + g * 4);
        u16x4 ha;
        ha[0] = __builtin_bit_cast(unsigned short, (_Float16)a.x);
        ha[1] = __builtin_bit_cast(unsigned short, (_Float16)a.y);
        ha[2] = __builtin_bit_cast(unsigned short, (_Float16)a.z);
        ha[3] = __builtin_bit_cast(unsigned short, (_Float16)a.w);
        *(u16x4*)((unsigned short*)scs + row * 68 + g * 4) = ha;
    }

    // ---- per-lane staging sources (16B slot pre-XOR'd with row&7) ----
    // x: 2 gl_lds/wave, rows 8w+4j+lr4
    const unsigned short* xg[2];
    #pragma unroll
    for (int j = 0; j < 2; ++j) {
        int row = 8 * w + 4 * j + lr4;
        xg[j] = xb + (size_t)row * IN_F + kh * 4096 + ((slot ^ (row & 7)) << 3);
    }
    _Float16* xd0 = xs + (8 * w) * 128;          // + buf*8192 (+512 for j=1)
    // W: 1 gl_lds/wave, rows 4w+lr4
    const int wrow = 4 * w + lr4;
    const int* wg = packed + (size_t)(n0 + wrow) * (IN_F / 2) + kh * 2048 + ((slot ^ (wrow & 7)) << 2);
    int* wd = wt + (4 * w) * 64;                 // + buf*2048

    // ---- loop-invariant swizzled read offsets ----
    const int r7 = c16 & 7;
    const int ks = (4 * wkk + q) ^ r7;           // swizzled 16B slot
    const int pvo = (nh * 16 + c16) * 64 + (ks << 2);
    int afo[4];
    #pragma unroll
    for (int mt = 0; mt < 4; ++mt)
        afo[mt] = (mt * 16 + c16) * 128 + (ks << 3);
    const int scso = (nh * 16 + c16) * 68 + (wkk >> 1);

    f32x4 acc[4];
    #pragma unroll
    for (int mt = 0; mt < 4; ++mt) acc[mt] = (f32x4){0.f, 0.f, 0.f, 0.f};

    // ---- prologue: stage chunks 0,1 -> buffers 0,1 ----
    #pragma unroll
    for (int c = 0; c < 2; ++c) {
        gl_lds16(xg[0] + (size_t)c * 128, xd0 + c * 8192);
        gl_lds16(xg[1] + (size_t)c * 128, xd0 + c * 8192 + 512);
        gl_lds16(wg + (size_t)c * 64, wd + c * 2048);
    }
    asm volatile("s_waitcnt lgkmcnt(0)" ::: "memory");   // scs visible
    __builtin_amdgcn_s_barrier();

    const f16x2 c1032 = {(_Float16)1032.0f, (_Float16)1032.0f};

    for (int kt = 0; kt < 32; ++kt) {
        // chunk kt resident (next chunk's 3 ops may fly); barrier; issue kt+2
        if (kt < 31) VMCNT(3);
        else         VMCNT(0);
        __builtin_amdgcn_s_barrier();
        __builtin_amdgcn_sched_barrier(0);
        const int cb = kt % 3;
        if (kt <= 29) {
            const int nb = (kt + 2) % 3;
            const size_t xo = (size_t)(kt + 2) * 128;
            gl_lds16(xg[0] + xo, xd0 + nb * 8192);
            gl_lds16(xg[1] + xo, xd0 + nb * 8192 + 512);
            gl_lds16(wg + (size_t)(kt + 2) * 64, wd + nb * 2048);
        }
        i32x4 pv = *(const i32x4*)(wt + cb * 2048 + pvo);
        _Float16 sch = scs[scso + kt * 2];
        f16x2 sc2 = {sch, sch};
        f16x8 bf;
        #pragma unroll
        for (int m = 0; m < 4; ++m) {
            unsigned u = ((((unsigned)pv[m] << 12) | (unsigned)pv[m]) & 0x000F000Fu) | 0x64006400u;
            f16x2 h = __builtin_bit_cast(f16x2, u);
            h = (h - c1032) * sc2;          // exact (q-8)*scale
            bf[2 * m] = h.x;
            bf[2 * m + 1] = h.y;
        }
        const _Float16* xbase = xs + cb * 8192;
        #pragma unroll
        for (int mt = 0; mt < 4; ++mt) {
            f16x8 af = *(const f16x8*)(xbase + afo[mt]);
            acc[mt] = __builtin_amdgcn_mfma_f32_16x16x32_f16(af, bf, acc[mt], 0, 0, 0);
        }
    }
    __syncthreads();   // all waves done with xs/wt before alias overwrite

    // ---- epilogue: partials -> LDS, reduce 4 k-waves, f32x4 store to pb ----
    float* myacc = accs + w * (64 * 17);
    #pragma unroll
    for (int mt = 0; mt < 4; ++mt)
        #pragma unroll
        for (int r = 0; r < 4; ++r)
            myacc[(mt * 16 + q * 4 + r) * 17 + c16] = acc[mt][r];
    __syncthreads();

    {
        const int base = tid * 4;
        f32x4 v4;
        #pragma unroll
        for (int j = 0; j < 4; ++j) {
            int p = base + j;
            int s = p >> 5, c = p & 31;
            const float* ab = accs + (c >> 4) * 4 * (64 * 17) + s * 17 + (c & 15);
            v4[j] = ab[0] + ab[64 * 17] + ab[2 * 64 * 17] + ab[3 * 64 * 17];
        }
        *(f32x4*)(pb + ((size_t)(kh * 256 + tile)) * 2048 + base) = v4;
    }
}

// ---- reduce: out = pb[kh0] + pb[kh1] + 2 * (x@A^T) @ B^T. 256 blocks. ----
__global__ __launch_bounds__(512) void k_reduce(
    const float* __restrict__ pb, const float* __restrict__ t,
    const float* __restrict__ B, float* __restrict__ out) {
    __shared__ float tred[64 * 17];
    __shared__ float bs[32 * 17];
    const int tid = threadIdx.x;
    const int tile = blockIdx.x, n0 = tile * 32;

    #pragma unroll
    for (int jj = 0; jj < 2; ++jj) {
        int p2 = tid + jj * 512;                  // 1024 = 64 s x 16 r
        int s = p2 >> 4, r = p2 & 15;
        const float* tp = t + s * 64 + r;
        tred[s * 17 + r] = tp[0] + tp[16] + tp[32] + tp[48];
    }
    {
        int row = tid >> 4, r = tid & 15;         // 512 = 32 rows x 16 r
        bs[row * 17 + r] = B[(size_t)(n0 + row) * LORA_R + r];
    }
    __syncthreads();

    const int base = tid * 4;
    const float* p0 = pb + (size_t)tile * 2048 + base;
    const float* p1 = pb + (size_t)(256 + tile) * 2048 + base;
    f32x4 a = *(const f32x4*)p0;
    f32x4 b = *(const f32x4*)p1;
    f32x4 v4;
    const int s = base >> 5;                      // same s for all 4 lanes' j
    const float* trow = tred + s * 17;
    #pragma unroll
    for (int j = 0; j < 4; ++j) {
        int c = (base + j) & 31;
        const float* brow = bs + c * 17;
        float lr = 0.f;
        #pragma unroll
        for (int r = 0; r < 16; ++r) lr = fmaf(trow[r], brow[r], lr);
        v4[j] = a[j] + b[j] + 2.0f * lr;
    }
    *(f32x4*)(out + (size_t)s * OUT_F + n0 + (base & 31)) = v4;
}

extern "C" void kernel_launch(void* const* d_in, const int* in_sizes, int n_in,
                              void* d_out, int out_size, void* d_ws, size_t ws_size,
                              hipStream_t stream) {
    const float* x      = (const float*)d_in[0];
    const int* packed   = (const int*)d_in[1];
    const float* scales = (const float*)d_in[2];
    const float* lora_A = (const float*)d_in[3];
    const float* lora_B = (const float*)d_in[4];
    float* out = (float*)d_out;

    unsigned short* xb = (unsigned short*)d_ws;                    // 1 MiB fp16 x
    float* t  = (float*)((char*)d_ws + (size_t)SEQ * IN_F * 2);    // 16 KiB partials
    float* pb = (float*)((char*)d_ws + 2 * 1024 * 1024);           // 4 MiB partials

    k_prep<<<256, 256, 0, stream>>>(x, lora_A, xb, t);
    k_main<<<512, 512, 0, stream>>>(packed, scales, xb, pb);
    k_reduce<<<256, 512, 0, stream>>>(pb, t, lora_B, out);
}